// Round 2
// baseline (180.897 us; speedup 1.0000x reference)
//
#include <hip/hip_runtime.h>
#include <math.h>

typedef unsigned short u16;
typedef unsigned int u32;
typedef __attribute__((ext_vector_type(4))) float f32x4;
typedef __attribute__((ext_vector_type(8))) short s16x8;
typedef __attribute__((ext_vector_type(4))) unsigned short u16x4;

#define T_ 2048
#define C_ 1024

// fp32 -> bf16, round-half-up (max err 0.5 ulp, values always finite here)
__device__ __forceinline__ u16 f2b(float f) {
  u32 u = __builtin_bit_cast(u32, f);
  return (u16)((u + 0x8000u) >> 16);
}

__device__ __forceinline__ s16x8 pack8(float4 a, float4 b) {
  s16x8 r;
  r[0] = (short)f2b(a.x); r[1] = (short)f2b(a.y);
  r[2] = (short)f2b(a.z); r[3] = (short)f2b(a.w);
  r[4] = (short)f2b(b.x); r[5] = (short)f2b(b.y);
  r[6] = (short)f2b(b.z); r[7] = (short)f2b(b.w);
  return r;
}

// ---------------- kernel 0: weights fp32 [1024][64] x3 -> Wt bf16 [192][1024]
// transposed (k-contiguous), via LDS tile transpose (coalesced both sides).
// Softmax scale 1/8 AND log2(e) folded into W_q (softmax done in exp2 domain).
__global__ __launch_bounds__(256) void wconv(const float* __restrict__ Wq,
                                             const float* __restrict__ Wk,
                                             const float* __restrict__ Wv,
                                             u16* __restrict__ Wt) {
  __shared__ u16 t[64][68];
  const int bm = blockIdx.x >> 4;   // matrix 0..2
  const int kt = blockIdx.x & 15;   // k-tile of 64
  const float* src = (bm == 0) ? Wq : ((bm == 1) ? Wk : Wv);
  const float scale = (bm == 0) ? 0.18033688f : 1.0f;  // 0.125 * log2(e)
  const int krow = threadIdx.x >> 2;        // 0..63
  const int c0 = (threadIdx.x & 3) * 16;    // 0,16,32,48
  const float* sp = src + (size_t)(kt * 64 + krow) * 64 + c0;
#pragma unroll
  for (int i = 0; i < 4; ++i) {
    float4 v = *(const float4*)(sp + i * 4);
    t[c0 + i * 4 + 0][krow] = f2b(v.x * scale);
    t[c0 + i * 4 + 1][krow] = f2b(v.y * scale);
    t[c0 + i * 4 + 2][krow] = f2b(v.z * scale);
    t[c0 + i * 4 + 3][krow] = f2b(v.w * scale);
  }
  __syncthreads();
  const int n = threadIdx.x >> 2;
  const int koff = (threadIdx.x & 3) * 16;
  u16* dst = Wt + (size_t)(bm * 64 + n) * C_ + kt * 64 + koff;
#pragma unroll
  for (int i = 0; i < 4; ++i)
    *(u16x4*)(dst + i * 4) = *(const u16x4*)(&t[n][koff + i * 4]);
}

// ---------------- kernel 1: qkv projection, bf16 MFMA, NO LDS / NO barriers.
// x [16384][1024] fp32 streamed straight into A-frags (reg convert to bf16);
// W B-frags read directly from L2-resident Wt. M=32/block, grid 512,
// 4 waves = 2 m-subtiles x 2 n-halves. Explicit next-K-tile x prefetch.
__global__ __launch_bounds__(256, 3) void proj(const float* __restrict__ x,
                                               const u16* __restrict__ Wt,
                                               u16* __restrict__ qo,
                                               u16* __restrict__ ko,
                                               u16* __restrict__ vt) {
  const int tid = threadIdx.x;
  const int wave = tid >> 6, lane = tid & 63;
  const int quad = lane >> 4, l15 = lane & 15;
  const int m = wave & 1, nh = wave >> 1;
  const int m0 = blockIdx.x * 32;

  const float* xr = x + (size_t)(m0 + m * 16 + l15) * C_ + quad * 8;
  const u16* wb = Wt + (size_t)(nh * 96 + l15) * C_ + quad * 8;

  f32x4 acc[6];
#pragma unroll
  for (int j = 0; j < 6; ++j) acc[j] = {0.f, 0.f, 0.f, 0.f};

  float4 xn0a = *(const float4*)(xr + 0);
  float4 xn0b = *(const float4*)(xr + 4);
  float4 xn1a = *(const float4*)(xr + 32);
  float4 xn1b = *(const float4*)(xr + 36);

  for (int kt = 0; kt < 16; ++kt) {
    float4 c0a = xn0a, c0b = xn0b, c1a = xn1a, c1b = xn1b;
    if (kt < 15) {  // prefetch next K-tile (HBM); overlaps MFMA + W loads below
      const float* p = xr + (kt + 1) * 64;
      xn0a = *(const float4*)(p + 0);
      xn0b = *(const float4*)(p + 4);
      xn1a = *(const float4*)(p + 32);
      xn1b = *(const float4*)(p + 36);
    }
    s16x8 a0 = pack8(c0a, c0b);
    s16x8 a1 = pack8(c1a, c1b);
    const u16* wk = wb + kt * 64;
    s16x8 w0[6], w1[6];
#pragma unroll
    for (int j = 0; j < 6; ++j) {
      w0[j] = *(const s16x8*)(wk + (size_t)j * 16 * C_);
      w1[j] = *(const s16x8*)(wk + (size_t)j * 16 * C_ + 32);
    }
#pragma unroll
    for (int j = 0; j < 6; ++j)
      acc[j] = __builtin_amdgcn_mfma_f32_16x16x32_bf16(a0, w0[j], acc[j], 0, 0, 0);
#pragma unroll
    for (int j = 0; j < 6; ++j)
      acc[j] = __builtin_amdgcn_mfma_f32_16x16x32_bf16(a1, w1[j], acc[j], 0, 0, 0);
  }

  // epilogue: C layout col=lane&15 (W-row = out col), row=quad*4+i (x row)
  const int r0 = m0 + m * 16 + quad * 4;
#pragma unroll
  for (int j = 0; j < 6; ++j) {
    const int ns = nh * 6 + j;
    if (ns < 4) {
      const int col = ns * 16 + l15;
#pragma unroll
      for (int i = 0; i < 4; ++i)
        qo[(size_t)(r0 + i) * 64 + col] = f2b(acc[j][i]);
    } else if (ns < 8) {
      const int col = (ns - 4) * 16 + l15;
#pragma unroll
      for (int i = 0; i < 4; ++i)
        ko[(size_t)(r0 + i) * 64 + col] = f2b(acc[j][i]);
    } else {
      const int d = (ns - 8) * 16 + l15;
      const int bb = r0 >> 11;
      const int t0 = r0 & 2047;
      u16x4 pk = {f2b(acc[j][0]), f2b(acc[j][1]), f2b(acc[j][2]), f2b(acc[j][3])};
      *(u16x4*)(vt + (size_t)bb * (64 * T_) + (size_t)d * T_ + t0) = pk;
    }
  }
}

// ---------------- kernel 2: causal flash attention
// block = (q-tile of 64, batch); 4 waves; wave w owns kv-tiles j = w, w+4, ...
// with private online-softmax state; partials merged at the end via LDS.
// S^T = K·Q^T (q in lane&15 -> 2-shuffle row reductions, packed P stores);
// PV as O^T = V^T·P^T. Softmax in exp2 domain (log2e folded into W_q).
__global__ __launch_bounds__(256, 1) void attn(const u16* __restrict__ qw,
                                               const u16* __restrict__ kw,
                                               const u16* __restrict__ vt,
                                               float* __restrict__ out) {
  __shared__ __align__(16) u16 Pb[4 * 64 * 72];  // per-wave P; reused for O
  __shared__ float mbuf[4][64];
  __shared__ float lbuf[4][64];
  const int tid = threadIdx.x;
  const int wave = tid >> 6, lane = tid & 63;
  const int quad = lane >> 4, l15 = lane & 15;
  const int qt = blockIdx.x, b = blockIdx.y;

  const u16* qp = qw + ((size_t)b * T_ + qt * 64) * 64;
  const u16* kb = kw + (size_t)b * T_ * 64;
  const u16* vb = vt + (size_t)b * 64 * T_;

  s16x8 qf[4][2];  // Q as B-operand: qf[nsub_q][kstep]
#pragma unroll
  for (int n = 0; n < 4; ++n)
#pragma unroll
    for (int ks = 0; ks < 2; ++ks)
      qf[n][ks] = *(const s16x8*)(qp + (16 * n + l15) * 64 + ks * 32 + quad * 8);

  f32x4 o[4][4];  // O^T accumulator: o[msub_d][nsub_q]
  float mr[4], lr[4];
#pragma unroll
  for (int m = 0; m < 4; ++m)
#pragma unroll
    for (int n = 0; n < 4; ++n) o[m][n] = {0.f, 0.f, 0.f, 0.f};
#pragma unroll
  for (int n = 0; n < 4; ++n) { mr[n] = -INFINITY; lr[n] = 0.0f; }

  u16* P = Pb + wave * (64 * 72);

  for (int j = wave; j <= qt; j += 4) {
    const u16* kp = kb + (size_t)j * 64 * 64;
    const u16* vp = vb + j * 64;
    f32x4 s[4][4];  // S^T: s[msub_kv][nsub_q]
#pragma unroll
    for (int m = 0; m < 4; ++m)
#pragma unroll
      for (int n = 0; n < 4; ++n) s[m][n] = {0.f, 0.f, 0.f, 0.f};
#pragma unroll
    for (int ks = 0; ks < 2; ++ks) {
      s16x8 kf[4];
#pragma unroll
      for (int m = 0; m < 4; ++m)
        kf[m] = *(const s16x8*)(kp + (16 * m + l15) * 64 + ks * 32 + quad * 8);
#pragma unroll
      for (int m = 0; m < 4; ++m)
#pragma unroll
        for (int n = 0; n < 4; ++n)
          s[m][n] = __builtin_amdgcn_mfma_f32_16x16x32_bf16(kf[m], qf[n][ks], s[m][n], 0, 0, 0);
    }
    if (j == qt) {  // diagonal tile: kv col c = 16m+quad*4+i, q row r = 16n+l15
#pragma unroll
      for (int m = 0; m < 4; ++m)
#pragma unroll
        for (int n = 0; n < 4; ++n)
#pragma unroll
          for (int i = 0; i < 4; ++i)
            if (16 * m + quad * 4 + i > 16 * n + l15) s[m][n][i] = -INFINITY;
    }
    float al[4];
#pragma unroll
    for (int n = 0; n < 4; ++n) {
      float mt = s[0][n][0];
#pragma unroll
      for (int m = 0; m < 4; ++m)
#pragma unroll
        for (int i = 0; i < 4; ++i) mt = fmaxf(mt, s[m][n][i]);
      mt = fmaxf(mt, __shfl_xor(mt, 16));
      mt = fmaxf(mt, __shfl_xor(mt, 32));
      float mn = fmaxf(mr[n], mt);
      al[n] = exp2f(mr[n] - mn);  // exp2(-inf)=0 on first tile
      mr[n] = mn;
      float rs = 0.0f;
#pragma unroll
      for (int m = 0; m < 4; ++m)
#pragma unroll
        for (int i = 0; i < 4; ++i) {
          float p = exp2f(s[m][n][i] - mn);
          s[m][n][i] = p;
          rs += p;
        }
      rs += __shfl_xor(rs, 16);
      rs += __shfl_xor(rs, 32);
      lr[n] = lr[n] * al[n] + rs;
    }
    // P -> LDS row-major [q][kv] (stride 72), packed 8B stores (wave-private)
#pragma unroll
    for (int n = 0; n < 4; ++n)
#pragma unroll
      for (int m = 0; m < 4; ++m) {
        u16x4 pk = {f2b(s[m][n][0]), f2b(s[m][n][1]), f2b(s[m][n][2]), f2b(s[m][n][3])};
        *(u16x4*)(&P[(16 * n + l15) * 72 + 16 * m + quad * 4]) = pk;
      }
#pragma unroll
    for (int m = 0; m < 4; ++m)
#pragma unroll
      for (int n = 0; n < 4; ++n) o[m][n] *= al[n];
    // O^T += V^T (A, global L2) · P^T (B, LDS contiguous reads of P rows)
#pragma unroll
    for (int ks = 0; ks < 2; ++ks) {
      s16x8 vf[4], pf[4];
#pragma unroll
      for (int m = 0; m < 4; ++m)
        vf[m] = *(const s16x8*)(vp + (size_t)(16 * m + l15) * T_ + ks * 32 + quad * 8);
#pragma unroll
      for (int n = 0; n < 4; ++n)
        pf[n] = *(const s16x8*)(&P[(16 * n + l15) * 72 + ks * 32 + quad * 8]);
#pragma unroll
      for (int m = 0; m < 4; ++m)
#pragma unroll
        for (int n = 0; n < 4; ++n)
          o[m][n] = __builtin_amdgcn_mfma_f32_16x16x32_bf16(vf[m], pf[n], o[m][n], 0, 0, 0);
    }
  }
  // per-wave stats (value replicated across quads after xor16/32 reduce)
  if (quad == 0) {
#pragma unroll
    for (int n = 0; n < 4; ++n) {
      mbuf[wave][16 * n + l15] = mr[n];
      lbuf[wave][16 * n + l15] = lr[n];
    }
  }
  __syncthreads();  // all waves done with their P region before O reuse
  // O^T -> LDS as [q][d] bf16 over Pb, packed (i indexes consecutive d)
#pragma unroll
  for (int m = 0; m < 4; ++m)
#pragma unroll
    for (int n = 0; n < 4; ++n) {
      u16x4 pk = {f2b(o[m][n][0]), f2b(o[m][n][1]), f2b(o[m][n][2]), f2b(o[m][n][3])};
      *(u16x4*)(&Pb[wave * (64 * 72) + (16 * n + l15) * 72 + 16 * m + quad * 4]) = pk;
    }
  __syncthreads();
  // merge 4 wave-partials: lane handles q-row r, d-chunk cg
  const int r = wave * 16 + (lane >> 2);
  const int cg = (lane & 3) * 16;
  float fw[4];
  float mstar = -INFINITY, lsum = 0.0f;
#pragma unroll
  for (int w = 0; w < 4; ++w) mstar = fmaxf(mstar, mbuf[w][r]);
#pragma unroll
  for (int w = 0; w < 4; ++w) {
    fw[w] = exp2f(mbuf[w][r] - mstar);
    lsum += fw[w] * lbuf[w][r];
  }
  const float inv = 1.0f / lsum;
  float accv[16];
#pragma unroll
  for (int e = 0; e < 16; ++e) accv[e] = 0.0f;
#pragma unroll
  for (int w = 0; w < 4; ++w) {
#pragma unroll
    for (int h = 0; h < 2; ++h) {
      s16x8 vv = *(const s16x8*)(&Pb[w * (64 * 72) + r * 72 + cg + h * 8]);
#pragma unroll
      for (int e = 0; e < 8; ++e) {
        float f = __builtin_bit_cast(float, ((u32)(u16)vv[e]) << 16);
        accv[h * 8 + e] += fw[w] * f;
      }
    }
  }
  float* op = out + ((size_t)b * T_ + qt * 64 + r) * 64 + cg;
#pragma unroll
  for (int e = 0; e < 16; e += 4) {
    float4 st = {accv[e] * inv, accv[e + 1] * inv, accv[e + 2] * inv, accv[e + 3] * inv};
    *(float4*)(op + e) = st;
  }
}

extern "C" void kernel_launch(void* const* d_in, const int* in_sizes, int n_in,
                              void* d_out, int out_size, void* d_ws, size_t ws_size,
                              hipStream_t stream) {
  const float* x  = (const float*)d_in[0];
  const float* Wq = (const float*)d_in[1];
  const float* Wk = (const float*)d_in[2];
  const float* Wv = (const float*)d_in[3];
  float* out = (float*)d_out;
  char* ws = (char*)d_ws;
  u16* Wt = (u16*)ws;                                   // 192*1024*2 = 384 KB
  u16* q  = (u16*)(ws + 393216);                        // 2 MB
  u16* k  = (u16*)(ws + 393216 + 2097152);              // 2 MB
  u16* vT = (u16*)(ws + 393216 + 2 * 2097152);          // 2 MB
  hipLaunchKernelGGL(wconv, dim3(48), dim3(256), 0, stream, Wq, Wk, Wv, Wt);
  hipLaunchKernelGGL(proj, dim3(512), dim3(256), 0, stream, x, Wt, q, k, vT);
  hipLaunchKernelGGL(attn, dim3(32, 8), dim3(256), 0, stream, q, k, vT, out);
}

// Round 3
// 171.703 us; speedup vs baseline: 1.0535x; 1.0535x over previous
//
#include <hip/hip_runtime.h>
#include <math.h>

typedef unsigned short u16;
typedef unsigned int u32;
typedef __attribute__((ext_vector_type(4))) float f32x4;
typedef __attribute__((ext_vector_type(8))) short s16x8;
typedef __attribute__((ext_vector_type(4))) unsigned short u16x4;

#define T_ 2048
#define C_ 1024

// fp32 -> bf16, round-half-up (max err 0.5 ulp, values always finite here)
__device__ __forceinline__ u16 f2b(float f) {
  u32 u = __builtin_bit_cast(u32, f);
  return (u16)((u + 0x8000u) >> 16);
}

__device__ __forceinline__ s16x8 pack8(float4 a, float4 b) {
  s16x8 r;
  r[0] = (short)f2b(a.x); r[1] = (short)f2b(a.y);
  r[2] = (short)f2b(a.z); r[3] = (short)f2b(a.w);
  r[4] = (short)f2b(b.x); r[5] = (short)f2b(b.y);
  r[6] = (short)f2b(b.z); r[7] = (short)f2b(b.w);
  return r;
}

// ---------------- kernel 0: weights fp32 [1024][64] x3 -> Wt bf16 [192][1024]
// transposed (k-contiguous), via LDS tile transpose (coalesced both sides).
// Softmax scale 1/8 AND log2(e) folded into W_q (softmax done in exp2 domain).
__global__ __launch_bounds__(256) void wconv(const float* __restrict__ Wq,
                                             const float* __restrict__ Wk,
                                             const float* __restrict__ Wv,
                                             u16* __restrict__ Wt) {
  __shared__ u16 t[64][68];
  const int bm = blockIdx.x >> 4;   // matrix 0..2
  const int kt = blockIdx.x & 15;   // k-tile of 64
  const float* src = (bm == 0) ? Wq : ((bm == 1) ? Wk : Wv);
  const float scale = (bm == 0) ? 0.18033688f : 1.0f;  // 0.125 * log2(e)
  const int krow = threadIdx.x >> 2;        // 0..63
  const int c0 = (threadIdx.x & 3) * 16;    // 0,16,32,48
  const float* sp = src + (size_t)(kt * 64 + krow) * 64 + c0;
#pragma unroll
  for (int i = 0; i < 4; ++i) {
    float4 v = *(const float4*)(sp + i * 4);
    t[c0 + i * 4 + 0][krow] = f2b(v.x * scale);
    t[c0 + i * 4 + 1][krow] = f2b(v.y * scale);
    t[c0 + i * 4 + 2][krow] = f2b(v.z * scale);
    t[c0 + i * 4 + 3][krow] = f2b(v.w * scale);
  }
  __syncthreads();
  const int n = threadIdx.x >> 2;
  const int koff = (threadIdx.x & 3) * 16;
  u16* dst = Wt + (size_t)(bm * 64 + n) * C_ + kt * 64 + koff;
#pragma unroll
  for (int i = 0; i < 4; ++i)
    *(u16x4*)(dst + i * 4) = *(const u16x4*)(&t[n][koff + i * 4]);
}

// ---------------- kernel 1: qkv projection, bf16 MFMA, no LDS / no barriers.
// Fix vs R2: W loads issued FIRST each iter (MFMA waits vmcnt(W-only), the x
// prefetch stays in flight), and x prefetch is 2 k-tiles deep so the consumed
// frag finished ~2 iterations ago. M=32/block, grid 512 (2 blocks/CU).
__global__ __launch_bounds__(256, 4) void proj(const float* __restrict__ x,
                                               const u16* __restrict__ Wt,
                                               u16* __restrict__ qo,
                                               u16* __restrict__ ko,
                                               u16* __restrict__ vt) {
  const int tid = threadIdx.x;
  const int wave = tid >> 6, lane = tid & 63;
  const int quad = lane >> 4, l15 = lane & 15;
  const int m = wave & 1, nh = wave >> 1;
  const int m0 = blockIdx.x * 32;

  const float* xr = x + (size_t)(m0 + m * 16 + l15) * C_ + quad * 8;
  const u16* wb = Wt + (size_t)(nh * 96 + l15) * C_ + quad * 8;

  f32x4 acc[6];
#pragma unroll
  for (int j = 0; j < 6; ++j) acc[j] = {0.f, 0.f, 0.f, 0.f};

  // 2-deep x prefetch: cur = kt, nxt = kt+1
  float4 cur0 = *(const float4*)(xr + 0);
  float4 cur1 = *(const float4*)(xr + 4);
  float4 cur2 = *(const float4*)(xr + 32);
  float4 cur3 = *(const float4*)(xr + 36);
  float4 nxt0 = *(const float4*)(xr + 64);
  float4 nxt1 = *(const float4*)(xr + 68);
  float4 nxt2 = *(const float4*)(xr + 96);
  float4 nxt3 = *(const float4*)(xr + 100);

  for (int kt = 0; kt < 16; ++kt) {
    // 1) W loads for THIS tile (L2) — issued before the x prefetch so the
    //    MFMA wait leaves x outstanding.
    const u16* wk = wb + kt * 64;
    s16x8 w0[6], w1[6];
#pragma unroll
    for (int j = 0; j < 6; ++j) {
      w0[j] = *(const s16x8*)(wk + (size_t)j * 16 * C_);
      w1[j] = *(const s16x8*)(wk + (size_t)j * 16 * C_ + 32);
    }
    // 2) x prefetch for kt+2 (HBM) — consumed two iterations from now.
    float4 c0 = cur0, c1 = cur1, c2 = cur2, c3 = cur3;
    cur0 = nxt0; cur1 = nxt1; cur2 = nxt2; cur3 = nxt3;
    if (kt < 14) {
      const float* p = xr + (kt + 2) * 64;
      nxt0 = *(const float4*)(p + 0);
      nxt1 = *(const float4*)(p + 4);
      nxt2 = *(const float4*)(p + 32);
      nxt3 = *(const float4*)(p + 36);
    }
    // 3) convert + MFMA
    s16x8 a0 = pack8(c0, c1);
    s16x8 a1 = pack8(c2, c3);
#pragma unroll
    for (int j = 0; j < 6; ++j)
      acc[j] = __builtin_amdgcn_mfma_f32_16x16x32_bf16(a0, w0[j], acc[j], 0, 0, 0);
#pragma unroll
    for (int j = 0; j < 6; ++j)
      acc[j] = __builtin_amdgcn_mfma_f32_16x16x32_bf16(a1, w1[j], acc[j], 0, 0, 0);
  }

  // epilogue: C layout col=lane&15 (W-row = out col), row=quad*4+i (x row)
  const int r0 = m0 + m * 16 + quad * 4;
#pragma unroll
  for (int j = 0; j < 6; ++j) {
    const int ns = nh * 6 + j;
    if (ns < 4) {
      const int col = ns * 16 + l15;
#pragma unroll
      for (int i = 0; i < 4; ++i)
        qo[(size_t)(r0 + i) * 64 + col] = f2b(acc[j][i]);
    } else if (ns < 8) {
      const int col = (ns - 4) * 16 + l15;
#pragma unroll
      for (int i = 0; i < 4; ++i)
        ko[(size_t)(r0 + i) * 64 + col] = f2b(acc[j][i]);
    } else {
      const int d = (ns - 8) * 16 + l15;
      const int bb = r0 >> 11;
      const int t0 = r0 & 2047;
      u16x4 pk = {f2b(acc[j][0]), f2b(acc[j][1]), f2b(acc[j][2]), f2b(acc[j][3])};
      *(u16x4*)(vt + (size_t)bb * (64 * T_) + (size_t)d * T_ + t0) = pk;
    }
  }
}

// ---------------- kernel 2: causal flash attention
// q-tile = 32 rows; grid = 512 linear blocks with b = blk&7 (XCD-affine: one
// batch's K/V per XCD L2), qt = blk>>3. 4 waves split kv-tiles (j = w, w+4..)
// with private online-softmax state; merged at the end via LDS.
// S^T = K·Q^T (q in lane&15 -> 2-shuffle row reductions, packed P stores);
// PV as O^T = V^T·P^T. V frags loaded BEFORE softmax (independent of S).
__global__ __launch_bounds__(256, 2) void attn(const u16* __restrict__ qw,
                                               const u16* __restrict__ kw,
                                               const u16* __restrict__ vt,
                                               float* __restrict__ out) {
  __shared__ __align__(16) u16 Pb[4 * 32 * 72];  // per-wave P; reused for O
  __shared__ float mbuf[4][32];
  __shared__ float lbuf[4][32];
  const int tid = threadIdx.x;
  const int wave = tid >> 6, lane = tid & 63;
  const int quad = lane >> 4, l15 = lane & 15;
  const int b = blockIdx.x & 7, qt = blockIdx.x >> 3;  // qt 0..63

  const u16* qp = qw + ((size_t)b * T_ + qt * 32) * 64;
  const u16* kb = kw + (size_t)b * T_ * 64;
  const u16* vb = vt + (size_t)b * 64 * T_;

  s16x8 qf[2][2];  // Q as B-operand: qf[nsub_q][kstep]
#pragma unroll
  for (int n = 0; n < 2; ++n)
#pragma unroll
    for (int ks = 0; ks < 2; ++ks)
      qf[n][ks] = *(const s16x8*)(qp + (16 * n + l15) * 64 + ks * 32 + quad * 8);

  f32x4 o[4][2];  // O^T accumulator: o[msub_d][nsub_q]
  float mr[2], lr[2];
#pragma unroll
  for (int m = 0; m < 4; ++m)
#pragma unroll
    for (int n = 0; n < 2; ++n) o[m][n] = {0.f, 0.f, 0.f, 0.f};
#pragma unroll
  for (int n = 0; n < 2; ++n) { mr[n] = -INFINITY; lr[n] = 0.0f; }

  u16* P = Pb + wave * (32 * 72);
  const int jd = qt >> 1;  // last (diagonal-overlapping) kv tile

  for (int j = wave; j <= jd; j += 4) {
    const u16* kp = kb + (size_t)j * 64 * 64;
    const u16* vp = vb + j * 64;
    // K frags (L2) then V frags (L2, independent of softmax -> early issue)
    s16x8 kf[2][4], vf[2][4];
#pragma unroll
    for (int ks = 0; ks < 2; ++ks)
#pragma unroll
      for (int m = 0; m < 4; ++m)
        kf[ks][m] = *(const s16x8*)(kp + (16 * m + l15) * 64 + ks * 32 + quad * 8);
#pragma unroll
    for (int ks = 0; ks < 2; ++ks)
#pragma unroll
      for (int m = 0; m < 4; ++m)
        vf[ks][m] = *(const s16x8*)(vp + (size_t)(16 * m + l15) * T_ + ks * 32 + quad * 8);

    f32x4 s[4][2];  // S^T: s[msub_kv][nsub_q]
#pragma unroll
    for (int m = 0; m < 4; ++m)
#pragma unroll
      for (int n = 0; n < 2; ++n) s[m][n] = {0.f, 0.f, 0.f, 0.f};
#pragma unroll
    for (int ks = 0; ks < 2; ++ks)
#pragma unroll
      for (int m = 0; m < 4; ++m)
#pragma unroll
        for (int n = 0; n < 2; ++n)
          s[m][n] = __builtin_amdgcn_mfma_f32_16x16x32_bf16(kf[ks][m], qf[n][ks], s[m][n], 0, 0, 0);

    if (j == jd) {  // diagonal tile: kv_g = 64j+16m+quad*4+i, q_g = 32qt+16n+l15
#pragma unroll
      for (int m = 0; m < 4; ++m)
#pragma unroll
        for (int n = 0; n < 2; ++n)
#pragma unroll
          for (int i = 0; i < 4; ++i)
            if (64 * jd + 16 * m + quad * 4 + i > 32 * qt + 16 * n + l15)
              s[m][n][i] = -INFINITY;
    }
    float al[2];
#pragma unroll
    for (int n = 0; n < 2; ++n) {
      float mt = s[0][n][0];
#pragma unroll
      for (int m = 0; m < 4; ++m)
#pragma unroll
        for (int i = 0; i < 4; ++i) mt = fmaxf(mt, s[m][n][i]);
      mt = fmaxf(mt, __shfl_xor(mt, 16));
      mt = fmaxf(mt, __shfl_xor(mt, 32));
      float mn = fmaxf(mr[n], mt);
      al[n] = exp2f(mr[n] - mn);  // exp2(-inf)=0 on first tile
      mr[n] = mn;
      float rs = 0.0f;
#pragma unroll
      for (int m = 0; m < 4; ++m)
#pragma unroll
        for (int i = 0; i < 4; ++i) {
          float p = exp2f(s[m][n][i] - mn);
          s[m][n][i] = p;
          rs += p;
        }
      rs += __shfl_xor(rs, 16);
      rs += __shfl_xor(rs, 32);
      lr[n] = lr[n] * al[n] + rs;
    }
    // P -> LDS row-major [q][kv] (stride 72), packed 8B stores (wave-private)
#pragma unroll
    for (int n = 0; n < 2; ++n)
#pragma unroll
      for (int m = 0; m < 4; ++m) {
        u16x4 pk = {f2b(s[m][n][0]), f2b(s[m][n][1]), f2b(s[m][n][2]), f2b(s[m][n][3])};
        *(u16x4*)(&P[(16 * n + l15) * 72 + 16 * m + quad * 4]) = pk;
      }
#pragma unroll
    for (int m = 0; m < 4; ++m)
#pragma unroll
      for (int n = 0; n < 2; ++n) o[m][n] *= al[n];
    // O^T += V^T (A, regs) · P^T (B, LDS contiguous reads of P rows)
#pragma unroll
    for (int ks = 0; ks < 2; ++ks) {
      s16x8 pf[2];
#pragma unroll
      for (int n = 0; n < 2; ++n)
        pf[n] = *(const s16x8*)(&P[(16 * n + l15) * 72 + ks * 32 + quad * 8]);
#pragma unroll
      for (int m = 0; m < 4; ++m)
#pragma unroll
        for (int n = 0; n < 2; ++n)
          o[m][n] = __builtin_amdgcn_mfma_f32_16x16x32_bf16(vf[ks][m], pf[n], o[m][n], 0, 0, 0);
    }
  }
  // per-wave stats (value replicated across quads after xor16/32 reduce)
  if (quad == 0) {
#pragma unroll
    for (int n = 0; n < 2; ++n) {
      mbuf[wave][16 * n + l15] = mr[n];
      lbuf[wave][16 * n + l15] = lr[n];
    }
  }
  __syncthreads();  // all waves done with their P region before O reuse
  // O^T -> LDS as [q][d] bf16 over Pb, packed (i indexes consecutive d)
#pragma unroll
  for (int m = 0; m < 4; ++m)
#pragma unroll
    for (int n = 0; n < 2; ++n) {
      u16x4 pk = {f2b(o[m][n][0]), f2b(o[m][n][1]), f2b(o[m][n][2]), f2b(o[m][n][3])};
      *(u16x4*)(&Pb[wave * (32 * 72) + (16 * n + l15) * 72 + 16 * m + quad * 4]) = pk;
    }
  __syncthreads();
  // merge 4 wave-partials: thread handles q-row r, 8-wide d-chunk cg
  const int r = tid >> 3;          // 0..31
  const int cg = (tid & 7) * 8;    // 0..56
  float fw[4];
  float mstar = -INFINITY, lsum = 0.0f;
#pragma unroll
  for (int w = 0; w < 4; ++w) mstar = fmaxf(mstar, mbuf[w][r]);
#pragma unroll
  for (int w = 0; w < 4; ++w) {
    fw[w] = exp2f(mbuf[w][r] - mstar);
    lsum += fw[w] * lbuf[w][r];
  }
  const float inv = 1.0f / lsum;
  float accv[8];
#pragma unroll
  for (int e = 0; e < 8; ++e) accv[e] = 0.0f;
#pragma unroll
  for (int w = 0; w < 4; ++w) {
    s16x8 vv = *(const s16x8*)(&Pb[w * (32 * 72) + r * 72 + cg]);
#pragma unroll
    for (int e = 0; e < 8; ++e) {
      float f = __builtin_bit_cast(float, ((u32)(u16)vv[e]) << 16);
      accv[e] += fw[w] * f;
    }
  }
  float* op = out + ((size_t)b * T_ + qt * 32 + r) * 64 + cg;
  float4 st0 = {accv[0] * inv, accv[1] * inv, accv[2] * inv, accv[3] * inv};
  float4 st1 = {accv[4] * inv, accv[5] * inv, accv[6] * inv, accv[7] * inv};
  *(float4*)(op + 0) = st0;
  *(float4*)(op + 4) = st1;
}

extern "C" void kernel_launch(void* const* d_in, const int* in_sizes, int n_in,
                              void* d_out, int out_size, void* d_ws, size_t ws_size,
                              hipStream_t stream) {
  const float* x  = (const float*)d_in[0];
  const float* Wq = (const float*)d_in[1];
  const float* Wk = (const float*)d_in[2];
  const float* Wv = (const float*)d_in[3];
  float* out = (float*)d_out;
  char* ws = (char*)d_ws;
  u16* Wt = (u16*)ws;                                   // 192*1024*2 = 384 KB
  u16* q  = (u16*)(ws + 393216);                        // 2 MB
  u16* k  = (u16*)(ws + 393216 + 2097152);              // 2 MB
  u16* vT = (u16*)(ws + 393216 + 2 * 2097152);          // 2 MB
  hipLaunchKernelGGL(wconv, dim3(48), dim3(256), 0, stream, Wq, Wk, Wv, Wt);
  hipLaunchKernelGGL(proj, dim3(512), dim3(256), 0, stream, x, Wt, q, k, vT);
  hipLaunchKernelGGL(attn, dim3(512), dim3(256), 0, stream, q, k, vT, out);
}